// Round 1
// baseline (65.648 us; speedup 1.0000x reference)
//
#include <hip/hip_runtime.h>
#include <math.h>

#define N_RAYS 131072
#define N_PTS  128
#define FAR_DELTA 1e10f

// One 64-lane wave per ray; lane i owns samples 2i and 2i+1.
// All global reads are coalesced (float2). Cumprod over 128 samples =
// per-lane product + 6-step shfl_up inclusive product scan across the wave.
__global__ __launch_bounds__(256) void volrender_kernel(
    const float* __restrict__ density,
    const float* __restrict__ feature,
    const float* __restrict__ depthv,
    float* __restrict__ out)
{
    const int lane = threadIdx.x & 63;
    const int ray  = blockIdx.x * 4 + (threadIdx.x >> 6);
    if (ray >= N_RAYS) return;

    const size_t rbase = (size_t)ray * N_PTS + 2 * lane;
    const float2 dv = *reinterpret_cast<const float2*>(depthv  + rbase);
    const float2 sg = *reinterpret_cast<const float2*>(density + rbase);

    const float* fb = feature + (size_t)ray * N_PTS * 3 + 6 * lane;
    const float2 fA = *reinterpret_cast<const float2*>(fb);      // f0.x f0.y
    const float2 fB = *reinterpret_cast<const float2*>(fb + 2);  // f0.z f1.x
    const float2 fC = *reinterpret_cast<const float2*>(fb + 4);  // f1.y f1.z

    // deltas: need depth of next sample; sample 2i+2 lives in lane i+1.
    const float dnext  = __shfl_down(dv.x, 1);
    const float delta0 = dv.y - dv.x;
    const float delta1 = (lane == 63) ? FAR_DELTA : (dnext - dv.y);

    const float t0 = expf(-sg.x * delta0);
    const float t1 = expf(-sg.y * delta1);

    // Inclusive product scan of per-lane product p = t0*t1 across 64 lanes.
    float scan = t0 * t1;
    #pragma unroll
    for (int off = 1; off < 64; off <<= 1) {
        const float v = __shfl_up(scan, off);
        if (lane >= off) scan *= v;
    }
    // Exclusive prefix: T at sample 2i.
    float excl = __shfl_up(scan, 1);
    if (lane == 0) excl = 1.0f;
    const float T0 = excl;
    const float T1 = excl * t0;

    // Alpha-compositing weights and RGB partial sums.
    const float w0 = T0 * (1.0f - t0);
    const float w1 = T1 * (1.0f - t1);
    float fx = w0 * fA.x + w1 * fB.y;
    float fy = w0 * fA.y + w1 * fC.x;
    float fz = w0 * fB.x + w1 * fC.y;

    // Depth estimate: keep samples with T < 1; depth = sum(t*dv)/sum(t).
    const float ts0 = (T0 < 1.0f) ? t0 : 0.0f;
    const float ts1 = (T1 < 1.0f) ? t1 : 0.0f;
    float st = ts0 + ts1;
    float sd = ts0 * dv.x + ts1 * dv.y;

    // Wave-wide butterfly reduction of the 5 partials.
    #pragma unroll
    for (int off = 32; off > 0; off >>= 1) {
        fx += __shfl_xor(fx, off);
        fy += __shfl_xor(fy, off);
        fz += __shfl_xor(fz, off);
        st += __shfl_xor(st, off);
        sd += __shfl_xor(sd, off);
    }

    if (lane == 0) {
        out[(size_t)ray * 3 + 0] = fx;
        out[(size_t)ray * 3 + 1] = fy;
        out[(size_t)ray * 3 + 2] = fz;
        const float dep = sd / st;
        out[(size_t)N_RAYS * 3 + ray] = (dep == 0.0f) ? INFINITY : dep;
    }
}

extern "C" void kernel_launch(void* const* d_in, const int* in_sizes, int n_in,
                              void* d_out, int out_size, void* d_ws, size_t ws_size,
                              hipStream_t stream) {
    const float* density = (const float*)d_in[0];
    const float* feature = (const float*)d_in[1];
    const float* depthv  = (const float*)d_in[2];
    float* out = (float*)d_out;

    const int rays_per_block = 4;                 // 256 threads = 4 waves
    const int grid = N_RAYS / rays_per_block;     // 32768 blocks
    volrender_kernel<<<grid, 256, 0, stream>>>(density, feature, depthv, out);
}